// Round 13
// baseline (394.382 us; speedup 1.0000x reference)
//
#include <hip/hip_runtime.h>
#include <hip/hip_bf16.h>

// EdgeBlock fused MLP:
//   out = relu(concat(edge, node[recv], node[send], g) @ W1 + b1) @ W2 + b2
// E=640000, N=10000, D=128, H=256, O=128.
//
// R13 = R12 with the compile fix: __builtin_nontemporal_load/store require
// native/ext_vector types, not HIP_vector_type float4 -> use f32x4.
//  1. NON-TEMPORAL edge loads + out stores: the 654MB streams no longer
//     sweep the 4MB per-XCD L2, so the 10MB Pr/Ps tables stay L2-resident
//     and the 655MB of gather demand becomes L2 hits instead of L3/HBM.
//  2. Gathers hoisted BEFORE staging (pinned by sched_barrier) so their
//     latency hides under stage+barrier+GEMM1; R5's VGPR=76 proves the
//     compiler was sinking them into consumers (acc64+gather64 > 76).
// Everything else (algebra, layouts, swizzles, barriers) is R5 verbatim:
//   Pr[n] = node[n] @ W1[128:256] + hbias, Ps[n] = node[n] @ W1[256:384]
//   h = relu(edge @ W1[0:128] + Pr[recv] + Ps[send]);  out = h @ W2 + b2

typedef __attribute__((ext_vector_type(8))) short bf16x8;
typedef __attribute__((ext_vector_type(4))) float f32x4;
typedef __attribute__((ext_vector_type(4))) unsigned int u32x4;
typedef __attribute__((ext_vector_type(2))) unsigned int u32x2;

#define NTILE 10000

static __device__ __forceinline__ unsigned short f2bf(float f) {
    unsigned u = __builtin_bit_cast(unsigned, f);
    u += 0x7FFFu + ((u >> 16) & 1u);
    return (unsigned short)(u >> 16);
}

static __device__ __forceinline__ unsigned cvt_pk_bf16(float lo, float hi) {
    unsigned r;
    asm("v_cvt_pk_bf16_f32 %0, %1, %2" : "=v"(r) : "v"(lo), "v"(hi));
    return r;
}

static __device__ __forceinline__ float bflo(unsigned u) {
    return __builtin_bit_cast(float, u << 16);
}
static __device__ __forceinline__ float bfhi(unsigned u) {
    return __builtin_bit_cast(float, u & 0xFFFF0000u);
}

// ---------------- prep kernels (unchanged from R5) ----------------

__global__ void prep_w1_kernel(const float* __restrict__ W1,
                               ushort* __restrict__ w1f) {
    int id = blockIdx.x * 256 + threadIdx.x;
    if (id >= 16 * 12 * 64) return;
    int l = id & 63, blk = id >> 6;
    int ks = blk % 12, gnt = blk / 12;
    int n  = gnt * 16 + (l & 15);
    int k0 = ks * 32 + (l >> 4) * 8;
    ushort tmp[8];
    #pragma unroll
    for (int j = 0; j < 8; ++j) tmp[j] = f2bf(W1[(k0 + j) * 256 + n]);
    *(bf16x8*)&w1f[(size_t)id * 8] = *(bf16x8*)tmp;
}

__global__ void prep_w2_kernel(const float* __restrict__ W2,
                               ushort* __restrict__ w2f) {
    int id = blockIdx.x * 256 + threadIdx.x;
    if (id >= 8 * 8 * 64) return;
    int l = id & 63, blk = id >> 6;
    int ks = blk % 8, gnt = blk / 8;
    int n  = gnt * 16 + (l & 15);
    int k0 = ks * 32 + (l >> 4) * 8;
    ushort tmp[8];
    #pragma unroll
    for (int j = 0; j < 8; ++j) tmp[j] = f2bf(W2[(k0 + j) * 128 + n]);
    *(bf16x8*)&w2f[(size_t)id * 8] = *(bf16x8*)tmp;
}

__global__ void prep_hbias_kernel(const float* __restrict__ W1,
                                  const float* __restrict__ b1,
                                  const float* __restrict__ g,
                                  float* __restrict__ hbias) {
    int n = threadIdx.x;
    float acc = b1[n];
    for (int k = 0; k < 128; ++k) acc += g[k] * W1[(384 + k) * 256 + n];
    hbias[n] = acc;
}

__global__ __launch_bounds__(256) void prep_proj_kernel(
    const float* __restrict__ node_attr,
    const ushort* __restrict__ w1f,
    const float* __restrict__ hbias,
    ushort* __restrict__ Pr,
    ushort* __restrict__ Ps)
{
    __shared__ ushort Xn[64 * 128];

    const int t = threadIdx.x, l = t & 63, wn = t >> 6;
    const int base = blockIdx.x * 64;
    const int lr = l & 15, q = l >> 4, lk = q * 8;

    #pragma unroll
    for (int p = 0; p < 4; ++p) {
        int chunk = p * 256 + t;
        int r  = chunk >> 4;
        int c0 = (chunk & 15) * 8;
        int node = base + r; if (node >= NTILE) node = NTILE - 1;
        const float4* src = (const float4*)(node_attr + (size_t)node * 128 + c0);
        float4 a = src[0];
        float4 b = src[1];
        uint4 uu = { cvt_pk_bf16(a.x, a.y), cvt_pk_bf16(a.z, a.w),
                     cvt_pk_bf16(b.x, b.y), cvt_pk_bf16(b.z, b.w) };
        *(bf16x8*)&Xn[r * 128 + (c0 ^ ((r & 7) << 3))] = __builtin_bit_cast(bf16x8, uu);
    }
    __syncthreads();

    #pragma unroll
    for (int s = 0; s < 2; ++s) {
        f32x4 acc[4][4];
        #pragma unroll
        for (int mt = 0; mt < 4; ++mt)
            #pragma unroll
            for (int nt = 0; nt < 4; ++nt)
                acc[mt][nt] = (f32x4){0.f, 0.f, 0.f, 0.f};

        #pragma unroll
        for (int ks = 0; ks < 4; ++ks) {
            bf16x8 B[4];
            #pragma unroll
            for (int nt = 0; nt < 4; ++nt)
                B[nt] = *(const bf16x8*)&w1f[
                    (size_t)(((wn * 4 + nt) * 12 + 4 + s * 4 + ks) * 64 + l) * 8];
            bf16x8 X[4];
            const int kk = ks * 32 + lk;
            #pragma unroll
            for (int mt = 0; mt < 4; ++mt) {
                const int row = mt * 16 + lr;
                X[mt] = *(const bf16x8*)&Xn[row * 128 + (kk ^ ((row & 7) << 3))];
            }
            #pragma unroll
            for (int mt = 0; mt < 4; ++mt)
                #pragma unroll
                for (int nt = 0; nt < 4; ++nt)
                    acc[mt][nt] = __builtin_amdgcn_mfma_f32_16x16x32_bf16(
                        B[nt], X[mt], acc[mt][nt], 0, 0, 0);
        }

        ushort* P = s ? Ps : Pr;
        #pragma unroll
        for (int nt = 0; nt < 4; ++nt) {
            const int F = wn * 64 + nt * 16 + q * 4;
            float4 hb4 = {0.f, 0.f, 0.f, 0.f};
            if (s == 0) hb4 = *(const float4*)&hbias[F];
            #pragma unroll
            for (int mt = 0; mt < 4; ++mt) {
                const int node = base + mt * 16 + lr;
                if (node < NTILE) {
                    u32x2 w = { cvt_pk_bf16(acc[mt][nt][0] + hb4.x,
                                            acc[mt][nt][1] + hb4.y),
                                cvt_pk_bf16(acc[mt][nt][2] + hb4.z,
                                            acc[mt][nt][3] + hb4.w) };
                    *(u32x2*)&P[(size_t)node * 256 + F] = w;
                }
            }
        }
    }
}

// ---------------- main fused kernel (R5 + nt streams + gather hoist) -------

__global__ __launch_bounds__(256, 3) void edge_mlp_kernel(
    const float* __restrict__ edge_attr,   // [E][128] f32
    const int* __restrict__ senders,
    const int* __restrict__ receivers,
    const ushort* __restrict__ w1f,        // frag-packed (ks 0..3 used)
    const ushort* __restrict__ w2f,        // frag-packed
    const ushort* __restrict__ Pr,         // [10000][256] bf16 (has hbias)
    const ushort* __restrict__ Ps,         // [10000][256] bf16
    const float* __restrict__ b2,          // [128]
    float* __restrict__ out)               // [E][128] f32
{
    __shared__ ushort Xe[64 * 128];   // 16 KiB, swizzled
    __shared__ ushort Hs[64 * 256];   // 32 KiB, swizzled

    const int t    = threadIdx.x;
    const int l    = t & 63;
    const int wid  = t >> 6;      // 0..3 : feat quarter
    const int base = blockIdx.x * 64;

    const int lr = l & 15;
    const int q  = l >> 4;
    const int lk = q * 8;

    // ---- indices ----
    int pr_off[4], ps_off[4];
    #pragma unroll
    for (int mt = 0; mt < 4; ++mt) {
        int e = base + mt * 16 + lr;
        pr_off[mt] = receivers[e] * 256;
        ps_off[mt] = senders[e]   * 256;
    }

    // ---- P gathers HOISTED: 32 x 8B issued before staging; latency
    //      hides under stage + barrier + GEMM1. sched_barrier pins them. ----
    u32x2 pg[4][4], sg[4][4];   // [nt][mt]
    #pragma unroll
    for (int nt = 0; nt < 4; ++nt) {
        const int F = wid * 64 + nt * 16 + q * 4;
        #pragma unroll
        for (int mt = 0; mt < 4; ++mt) {
            pg[nt][mt] = *(const u32x2*)&Pr[pr_off[mt] + F];
            sg[nt][mt] = *(const u32x2*)&Ps[ps_off[mt] + F];
        }
    }
    __builtin_amdgcn_sched_barrier(0);

    // ---- stage edge segment: NON-TEMPORAL f32 loads -> bf16 swizzled Xe ---
    #pragma unroll
    for (int p = 0; p < 4; ++p) {
        int chunk = p * 256 + t;
        int r  = chunk >> 4;
        int c0 = (chunk & 15) * 8;
        const f32x4* src = (const f32x4*)(edge_attr + (size_t)(base + r) * 128 + c0);
        f32x4 a = __builtin_nontemporal_load(src);
        f32x4 b = __builtin_nontemporal_load(src + 1);
        uint4 uu = { cvt_pk_bf16(a.x, a.y), cvt_pk_bf16(a.z, a.w),
                     cvt_pk_bf16(b.x, b.y), cvt_pk_bf16(b.z, b.w) };
        *(bf16x8*)&Xe[r * 128 + (c0 ^ ((r & 7) << 3))] = __builtin_bit_cast(bf16x8, uu);
    }

    __syncthreads();

    // ---- GEMM1': D row = hidden feat, col = edge; K = 128 from Xe ----
    f32x4 acc[4][4];
    #pragma unroll
    for (int mt = 0; mt < 4; ++mt)
        #pragma unroll
        for (int nt = 0; nt < 4; ++nt)
            acc[mt][nt] = (f32x4){0.f, 0.f, 0.f, 0.f};

    bf16x8 B[2][4];
    #pragma unroll
    for (int nt = 0; nt < 4; ++nt)
        B[0][nt] = *(const bf16x8*)&w1f[(size_t)(((wid * 4 + nt) * 12 + 0) * 64 + l) * 8];

    #pragma unroll
    for (int ks = 0; ks < 4; ++ks) {
        const int cur = ks & 1;
        if (ks < 3) {
            #pragma unroll
            for (int nt = 0; nt < 4; ++nt)
                B[cur ^ 1][nt] = *(const bf16x8*)&w1f[
                    (size_t)(((wid * 4 + nt) * 12 + (ks + 1)) * 64 + l) * 8];
        }
        bf16x8 X[4];
        const int kk = ks * 32 + lk;
        #pragma unroll
        for (int mt = 0; mt < 4; ++mt) {
            const int row = mt * 16 + lr;
            X[mt] = *(const bf16x8*)&Xe[row * 128 + (kk ^ ((row & 7) << 3))];
        }
        #pragma unroll
        for (int mt = 0; mt < 4; ++mt)
            #pragma unroll
            for (int nt = 0; nt < 4; ++nt)
                acc[mt][nt] = __builtin_amdgcn_mfma_f32_16x16x32_bf16(
                    B[cur][nt], X[mt], acc[mt][nt], 0, 0, 0);
    }

    // ---- epilogue 1: acc + Pr + Ps (already in regs), relu, -> Hs ----
    #pragma unroll
    for (int nt = 0; nt < 4; ++nt) {
        const int F = wid * 64 + nt * 16 + q * 4;
        #pragma unroll
        for (int mt = 0; mt < 4; ++mt) {
            u32x2 p = pg[nt][mt], s = sg[nt][mt];
            float v0 = fmaxf(acc[mt][nt][0] + bflo(p.x) + bflo(s.x), 0.f);
            float v1 = fmaxf(acc[mt][nt][1] + bfhi(p.x) + bfhi(s.x), 0.f);
            float v2 = fmaxf(acc[mt][nt][2] + bflo(p.y) + bflo(s.y), 0.f);
            float v3 = fmaxf(acc[mt][nt][3] + bfhi(p.y) + bfhi(s.y), 0.f);
            u32x2 w = { cvt_pk_bf16(v0, v1), cvt_pk_bf16(v2, v3) };
            const int edge = mt * 16 + lr;
            *(u32x2*)&Hs[edge * 256 + (F ^ ((edge & 7) << 3))] = w;
        }
    }

    __syncthreads();

    // ---- GEMM2: D row = out feat, col = edge; K = 256 from Hs ----
    f32x4 acc2[4][2];
    #pragma unroll
    for (int mt = 0; mt < 4; ++mt)
        #pragma unroll
        for (int nt = 0; nt < 2; ++nt)
            acc2[mt][nt] = (f32x4){0.f, 0.f, 0.f, 0.f};

    bf16x8 W2b[2][2];
    #pragma unroll
    for (int nt = 0; nt < 2; ++nt)
        W2b[0][nt] = *(const bf16x8*)&w2f[(size_t)(((wid * 2 + nt) * 8 + 0) * 64 + l) * 8];

    #pragma unroll
    for (int ks = 0; ks < 8; ++ks) {
        const int cur = ks & 1;
        if (ks < 7) {
            #pragma unroll
            for (int nt = 0; nt < 2; ++nt)
                W2b[cur ^ 1][nt] = *(const bf16x8*)&w2f[
                    (size_t)(((wid * 2 + nt) * 8 + (ks + 1)) * 64 + l) * 8];
        }
        bf16x8 Hfr[4];
        const int F = ks * 32 + lk;
        #pragma unroll
        for (int mt = 0; mt < 4; ++mt) {
            const int edge = mt * 16 + lr;
            Hfr[mt] = *(const bf16x8*)&Hs[edge * 256 + (F ^ ((edge & 7) << 3))];
        }
        #pragma unroll
        for (int mt = 0; mt < 4; ++mt)
            #pragma unroll
            for (int nt = 0; nt < 2; ++nt)
                acc2[mt][nt] = __builtin_amdgcn_mfma_f32_16x16x32_bf16(
                    W2b[cur][nt], Hfr[mt], acc2[mt][nt], 0, 0, 0);
    }

    // ---- epilogue 2: +b2, NON-TEMPORAL 16B stores (f32x4) ----
    #pragma unroll
    for (int nt = 0; nt < 2; ++nt) {
        const int F = wid * 32 + nt * 16 + q * 4;
        float4 b24 = *(const float4*)&b2[F];
        #pragma unroll
        for (int mt = 0; mt < 4; ++mt) {
            f32x4 o = { acc2[mt][nt][0] + b24.x, acc2[mt][nt][1] + b24.y,
                        acc2[mt][nt][2] + b24.z, acc2[mt][nt][3] + b24.w };
            __builtin_nontemporal_store(o,
                (f32x4*)&out[(size_t)(base + mt * 16 + lr) * 128 + F]);
        }
    }
}

// ---------------- launcher ----------------

extern "C" void kernel_launch(void* const* d_in, const int* in_sizes, int n_in,
                              void* d_out, int out_size, void* d_ws, size_t ws_size,
                              hipStream_t stream) {
    (void)in_sizes; (void)n_in; (void)out_size; (void)ws_size;

    const float* edge_attr   = (const float*)d_in[0];
    const float* node_attr   = (const float*)d_in[1];
    const float* global_attr = (const float*)d_in[2];
    const int*   senders     = (const int*)d_in[3];
    const int*   receivers   = (const int*)d_in[4];
    const float* W1          = (const float*)d_in[5];
    const float* b1          = (const float*)d_in[6];
    const float* W2          = (const float*)d_in[7];
    const float* b2          = (const float*)d_in[8];
    float* out = (float*)d_out;

    ushort* w1f   = (ushort*)d_ws;                          //   196,608 B
    ushort* w2f   = (ushort*)((char*)d_ws + 196608);        //    65,536 B
    float*  hbias = (float*)((char*)d_ws + 262144);         //     1,024 B
    ushort* Pr    = (ushort*)((char*)d_ws + 263168);        // 5,120,000 B
    ushort* Ps    = (ushort*)((char*)d_ws + 5383168);       // 5,120,000 B

    hipLaunchKernelGGL(prep_w1_kernel,    dim3(48),  dim3(256), 0, stream, W1, w1f);
    hipLaunchKernelGGL(prep_w2_kernel,    dim3(16),  dim3(256), 0, stream, W2, w2f);
    hipLaunchKernelGGL(prep_hbias_kernel, dim3(1),   dim3(256), 0, stream, W1, b1, global_attr, hbias);
    hipLaunchKernelGGL(prep_proj_kernel,  dim3(157), dim3(256), 0, stream,
                       node_attr, w1f, hbias, Pr, Ps);

    hipLaunchKernelGGL(edge_mlp_kernel, dim3(10000), dim3(256), 0, stream,
                       edge_attr, senders, receivers, w1f, w2f, Pr, Ps, b2, out);
}